// Round 8
// baseline (615.553 us; speedup 1.0000x reference)
//
#include <hip/hip_runtime.h>
#include <hip/hip_bf16.h>
#include <cstdint>

// Problem constants (from reference)
#define TT     2048   // tokens
#define KSEL   6      // experts per token
#define DMODEL 2048   // model dim
#define DINTER 1408   // moe intermediate dim
#define NE     16     // routed experts
#define PMAX   (TT * KSEL)

typedef short bf16x8 __attribute__((ext_vector_type(8)));
typedef float f32x4 __attribute__((ext_vector_type(4)));
typedef unsigned short u16;
typedef u16 u16x8 __attribute__((ext_vector_type(8)));

__device__ __forceinline__ u16 f2bf(float f) {
  union { float f; unsigned u; } v; v.f = f;
  return (u16)((v.u + 0x7FFFu + ((v.u >> 16) & 1u)) >> 16);  // RNE
}

__device__ __forceinline__ void gl2lds16(const void* g, void* l) {
  __builtin_amdgcn_global_load_lds((const __attribute__((address_space(1))) void*)g,
                                   (__attribute__((address_space(3))) void*)l,
                                   16, 0, 0);
}

#define BOUNDARY(N) do { \
  asm volatile("s_waitcnt vmcnt(" #N ")" ::: "memory"); \
  __builtin_amdgcn_s_barrier(); \
} while (0)

// gate_w[t,e] = sum_k weights[t,k]*(indices[t,k]==e); count routed (t,e) pairs
__global__ void k_gate(const float* __restrict__ w, const int* __restrict__ idx,
                       float* __restrict__ gate_w, int* __restrict__ counts) {
  int g = blockIdx.x * 256 + threadIdx.x;  // T*E threads
  int t = g >> 4, e = g & 15;
  const int* ip = idx + t * KSEL;
  const float* wp = w + t * KSEL;
  float s = 0.f;
#pragma unroll
  for (int k = 0; k < KSEL; ++k) s += (ip[k] == e) ? wp[k] : 0.f;
  gate_w[g] = s;
  if (s != 0.f) atomicAdd(counts + e, 1);
}

__global__ void k_scan(const int* __restrict__ counts, int* __restrict__ offs) {
  if (threadIdx.x == 0 && blockIdx.x == 0) {
    int r = 0;
#pragma unroll
    for (int e = 0; e < NE; ++e) { offs[e] = r; r += counts[e]; }
    offs[NE] = r;
  }
}

__global__ void k_fill(const float* __restrict__ gate_w, const int* __restrict__ offs,
                       int* __restrict__ cursor, int* __restrict__ slot_tok,
                       float* __restrict__ slot_gate) {
  int g = blockIdx.x * 256 + threadIdx.x;
  int t = g >> 4, e = g & 15;
  float s = gate_w[g];
  if (s != 0.f) {
    int p = atomicAdd(cursor + e, 1);
    int sl = offs[e] + p;
    slot_tok[sl] = t;
    slot_gate[sl] = s;
  }
}

// single merged fp32->bf16 cast over 4 tensors (x, Wg, Wu, Wd), 8 elems/thread
#define XV8   (TT * DMODEL / 8)                      // 524288
#define WV8   (NE * DINTER * DMODEL / 8)             // 5767168
__global__ void k_castall(const float* __restrict__ x,  u16* __restrict__ xb,
                          const float* __restrict__ wg, u16* __restrict__ wgb,
                          const float* __restrict__ wu, u16* __restrict__ wub,
                          const float* __restrict__ wd, u16* __restrict__ wdb) {
  const int total = XV8 + 3 * WV8;
  int stride = gridDim.x * 256;
  for (int i = blockIdx.x * 256 + threadIdx.x; i < total; i += stride) {
    const float* src; u16* dst; int j;
    if (i < XV8)                { src = x;  dst = xb;  j = i; }
    else if (i < XV8 + WV8)     { src = wg; dst = wgb; j = i - XV8; }
    else if (i < XV8 + 2 * WV8) { src = wu; dst = wub; j = i - XV8 - WV8; }
    else                        { src = wd; dst = wdb; j = i - XV8 - 2 * WV8; }
    const float4* p = (const float4*)src + (size_t)j * 2;
    float4 v0 = p[0], v1 = p[1];
    u16x8 o;
    o[0] = f2bf(v0.x); o[1] = f2bf(v0.y); o[2] = f2bf(v0.z); o[3] = f2bf(v0.w);
    o[4] = f2bf(v1.x); o[5] = f2bf(v1.y); o[6] = f2bf(v1.z); o[7] = f2bf(v1.w);
    *(u16x8*)(dst + (size_t)j * 8) = o;
  }
}

// ---------------------------------------------------------------------------
// GEMM1, phase-scheduled (T3+T4+T5): BM=256(tokens) x BN=128(inter), BK=32,
// 8 waves (4M x 2N, 64x64 each, dual acc g/u). 4-buffer LDS ring, prefetch
// depth 2 tiles, boundary = vmcnt(4)+raw barrier (counted, never 0 in steady
// state). All buffer indices are compile-time literals (rule #20).
// LDS rows are 32 bf16 = 64 B = 4 16B-units; XOR swizzle u' = u ^ ((row>>1)&3)
// (row>>1 so even rows cycle all 4 quads -> 2 lanes/bank = free; row&3 would
// leave a 4-way conflict). Applied on BOTH global-source and ds_read (rule #21).
// ---------------------------------------------------------------------------
#define AB 8192   // u16 per A buffer (256*32)
#define GB 4096   // u16 per G/U buffer (128*32)

__global__ __launch_bounds__(512, 2) void k_gemm1(
    const u16* __restrict__ xb, const u16* __restrict__ wgb, const u16* __restrict__ wub,
    const int* __restrict__ slot_tok, const float* __restrict__ slot_gate,
    const int* __restrict__ offs, const int* __restrict__ counts,
    u16* __restrict__ act) {
  // grid flat = 8(mt) x 11(it) x 16(e) = 1408 = 8*176; XCD-chunked swizzle
  int b = blockIdx.x;
  int w = (b & 7) * 176 + (b >> 3);
  int mt = w & 7, rest = w >> 3;
  int it = rest % 11, e = rest / 11;

  int mcount = counts[e];
  if (mt * 256 >= mcount) return;
  int mrem = mcount - mt * 256; if (mrem > 256) mrem = 256;
  int slotBase = offs[e] + mt * 256;
  int iBase = it * 128;

  __shared__ u16 sA[4 * AB];   // 64 KB
  __shared__ u16 sG[4 * GB];   // 32 KB
  __shared__ u16 sU[4 * GB];   // 32 KB
  __shared__ int tokLds[256];
  __shared__ float gateLds[256];

  int tid = threadIdx.x;
  if (tid < 256) {
    int rl = tid < mrem ? tid : 0;
    tokLds[tid] = slot_tok[slotBase + rl];
    gateLds[tid] = (tid < mrem) ? slot_gate[slotBase + rl] : 0.f;
  }
  __syncthreads();

  int wv = tid >> 6, lane = tid & 63;
  // staging: chunks of 1KB = 16 rows x 64B; 4 lanes/row, 16B each.
  // A: 16 chunks (2/wave); G,U: 8 chunks (1/wave). 4 loads/thread/tile.
  int rIC = lane >> 2;                            // row within chunk
  int uSw = ((lane & 3) ^ ((rIC >> 1) & 3)) * 8;  // swizzled source col (u16)
  const u16 *aSrc0, *aSrc1, *gSrc, *uSrc;
  int aOff0, aOff1, gOff;
  {
    const u16* gBase = wgb + ((size_t)e * DINTER + iBase) * DMODEL;
    const u16* uBase = wub + ((size_t)e * DINTER + iBase) * DMODEL;
    int c0 = wv * 2, c1 = wv * 2 + 1;
    aSrc0 = xb + (size_t)tokLds[c0 * 16 + rIC] * DMODEL + uSw;
    aSrc1 = xb + (size_t)tokLds[c1 * 16 + rIC] * DMODEL + uSw;
    aOff0 = c0 * 512; aOff1 = c1 * 512;
    gSrc = gBase + (size_t)(wv * 16 + rIC) * DMODEL + uSw;
    uSrc = uBase + (size_t)(wv * 16 + rIC) * DMODEL + uSw;
    gOff = wv * 512;
  }

  f32x4 accg[4][4] = {};
  f32x4 accu[4][4] = {};
  int fr = lane & 15, fq = lane >> 4;
  int wr = (wv >> 1) * 64, wc = (wv & 1) * 64;
  // precompute swizzled ds_read offsets (row-dependent XOR)
  int aRd[4], bRd[4];
#pragma unroll
  for (int mf = 0; mf < 4; ++mf) {
    int row = wr + mf * 16 + fr;
    aRd[mf] = row * 32 + ((fq ^ ((row >> 1) & 3)) << 3);
  }
#pragma unroll
  for (int nf = 0; nf < 4; ++nf) {
    int row = wc + nf * 16 + fr;
    bRd[nf] = row * 32 + ((fq ^ ((row >> 1) & 3)) << 3);
  }

  auto STAGE4 = [&](int bs, int kS) {
    gl2lds16(aSrc0 + kS, &sA[bs * AB + aOff0]);
    gl2lds16(aSrc1 + kS, &sA[bs * AB + aOff1]);
    gl2lds16(gSrc + kS, &sG[bs * GB + gOff]);
    gl2lds16(uSrc + kS, &sU[bs * GB + gOff]);
  };

  // One BK=32 tile: 2 phases (G-phase, U-phase), 16 MFMA each, staged issue.
  auto TILE = [&](int bf, int bs, int kS, bool doStage) {
    // ---- phase G ----
    if (doStage) {
      gl2lds16(aSrc0 + kS, &sA[bs * AB + aOff0]);
      gl2lds16(aSrc1 + kS, &sA[bs * AB + aOff1]);
    }
    bf16x8 af[4], bg[4], bu[4];
#pragma unroll
    for (int mf = 0; mf < 4; ++mf) af[mf] = *(const bf16x8*)&sA[bf * AB + aRd[mf]];
#pragma unroll
    for (int nf = 0; nf < 4; ++nf) bg[nf] = *(const bf16x8*)&sG[bf * GB + bRd[nf]];
    __builtin_amdgcn_s_barrier();
    __builtin_amdgcn_s_setprio(1);
#pragma unroll
    for (int mf = 0; mf < 4; ++mf)
#pragma unroll
      for (int nf = 0; nf < 4; ++nf)
        accg[mf][nf] = __builtin_amdgcn_mfma_f32_16x16x32_bf16(af[mf], bg[nf], accg[mf][nf], 0, 0, 0);
    __builtin_amdgcn_s_setprio(0);
    __builtin_amdgcn_s_barrier();
    // ---- phase U ----
    if (doStage) {
      gl2lds16(gSrc + kS, &sG[bs * GB + gOff]);
      gl2lds16(uSrc + kS, &sU[bs * GB + gOff]);
    }
#pragma unroll
    for (int nf = 0; nf < 4; ++nf) bu[nf] = *(const bf16x8*)&sU[bf * GB + bRd[nf]];
    __builtin_amdgcn_s_barrier();
    __builtin_amdgcn_s_setprio(1);
#pragma unroll
    for (int mf = 0; mf < 4; ++mf)
#pragma unroll
      for (int nf = 0; nf < 4; ++nf)
        accu[mf][nf] = __builtin_amdgcn_mfma_f32_16x16x32_bf16(af[mf], bu[nf], accu[mf][nf], 0, 0, 0);
    __builtin_amdgcn_s_setprio(0);
  };

  // NT = 64 BK=32 tiles. Prologue: stage t0,t1; steady: tile t stages t+2.
  STAGE4(0, 0);
  STAGE4(1, 32);
  BOUNDARY(4);                 // t0 landed; t1 (4 loads) in flight
#pragma unroll 1
  for (int t4 = 0; t4 < 60; t4 += 4) {
    TILE(0, 2, (t4 + 2) * 32, true);  BOUNDARY(4);
    TILE(1, 3, (t4 + 3) * 32, true);  BOUNDARY(4);
    TILE(2, 0, (t4 + 4) * 32, true);  BOUNDARY(4);
    TILE(3, 1, (t4 + 5) * 32, true);  BOUNDARY(4);
  }
  TILE(0, 2, 62 * 32, true);   BOUNDARY(4);
  TILE(1, 3, 63 * 32, true);   BOUNDARY(4);
  TILE(2, 0, 0, false);        BOUNDARY(0);
  TILE(3, 0, 0, false);

  // epilogue: act = silu(g)*u*gate -> bf16  (D layout: col=lane&15, row=(lane>>4)*4+r)
#pragma unroll
  for (int mf = 0; mf < 4; ++mf)
#pragma unroll
    for (int nf = 0; nf < 4; ++nf)
#pragma unroll
      for (int r = 0; r < 4; ++r) {
        int row = wr + mf * 16 + fq * 4 + r;
        if (row < mrem) {
          float g = accg[mf][nf][r], u = accu[mf][nf][r];
          float a = g / (1.f + __expf(-g)) * u * gateLds[row];
          act[(size_t)(slotBase + row) * DINTER + iBase + wc + nf * 16 + fr] = f2bf(a);
        }
      }
}

// GEMM2: y[tok, d] += act[slot,:] @ Wd[e,d,:]  (atomic scatter, <=6 adds/elem)
// known-good R6 structure: 128x128, BK=64, 4 waves, 2-phase, 8-unit XOR swizzle.
__global__ __launch_bounds__(256, 4) void k_gemm2(
    const u16* __restrict__ act, const u16* __restrict__ wdb,
    const int* __restrict__ slot_tok, const int* __restrict__ offs,
    const int* __restrict__ counts, float* __restrict__ y) {
  // grid flat = 16(mt) x 16(dt) x 16(e) = 4096 = 8*512
  int b = blockIdx.x;
  int w = (b & 7) * 512 + (b >> 3);
  int mt = w & 15, rest = w >> 4;
  int dt = rest & 15, e = rest >> 4;

  int mcount = counts[e];
  if (mt * 128 >= mcount) return;
  int mrem = mcount - mt * 128; if (mrem > 128) mrem = 128;
  int slotBase = offs[e] + mt * 128;
  int dBase = dt * 128;

  __shared__ u16 sA[128 * 64];
  __shared__ u16 sB[128 * 64];
  __shared__ int tokLds[128];

  int tid = threadIdx.x;
  if (tid < 128) tokLds[tid] = slot_tok[slotBase + (tid < mrem ? tid : 0)];
  __syncthreads();

  int wv = tid >> 6, lane = tid & 63;
  const u16 *aSrc[4], *bSrc[4];
  u16 *aDst[4], *bDst[4];
  const u16* bBase = wdb + ((size_t)e * DMODEL + dBase) * DINTER;
  int r8 = lane >> 3;
  int colOff = (((lane & 7) ^ r8)) * 8;   // swizzled 16B-unit
#pragma unroll
  for (int i2 = 0; i2 < 4; ++i2) {
    int chunk = wv * 4 + i2;
    int row = chunk * 8 + r8;
    aSrc[i2] = act + (size_t)(slotBase + row) * DINTER + colOff;  // act padded rows
    bSrc[i2] = bBase + (size_t)row * DINTER + colOff;
    aDst[i2] = sA + chunk * 512;
    bDst[i2] = sB + chunk * 512;
  }

  f32x4 acc[4][4] = {};
  int fr = lane & 15, fq = lane >> 4;
  int wr = (wv >> 1) * 64, wc = (wv & 1) * 64;

  for (int kb = 0; kb < DINTER / 64; ++kb) {
    int kOff = kb * 64;
    __syncthreads();
#pragma unroll
    for (int i2 = 0; i2 < 4; ++i2) {
      gl2lds16(aSrc[i2] + kOff, aDst[i2]);
      gl2lds16(bSrc[i2] + kOff, bDst[i2]);
    }
    __syncthreads();
#pragma unroll
    for (int kf = 0; kf < 2; ++kf) {
      bf16x8 af[4], bb[4];
#pragma unroll
      for (int mf = 0; mf < 4; ++mf) {
        int row = wr + mf * 16 + fr;
        int cu = ((kf * 4 + fq) ^ (row & 7)) * 8;
        af[mf] = *(const bf16x8*)&sA[row * 64 + cu];
      }
#pragma unroll
      for (int nf = 0; nf < 4; ++nf) {
        int row = wc + nf * 16 + fr;
        int cu = ((kf * 4 + fq) ^ (row & 7)) * 8;
        bb[nf] = *(const bf16x8*)&sB[row * 64 + cu];
      }
#pragma unroll
      for (int mf = 0; mf < 4; ++mf)
#pragma unroll
        for (int nf = 0; nf < 4; ++nf)
          acc[mf][nf] = __builtin_amdgcn_mfma_f32_16x16x32_bf16(af[mf], bb[nf], acc[mf][nf], 0, 0, 0);
    }
  }
#pragma unroll
  for (int mf = 0; mf < 4; ++mf)
#pragma unroll
    for (int nf = 0; nf < 4; ++nf)
#pragma unroll
      for (int r = 0; r < 4; ++r) {
        int row = wr + mf * 16 + fq * 4 + r;
        if (row < mrem) {
          int t = tokLds[row];
          atomicAdd(y + (size_t)t * DMODEL + dBase + wc + nf * 16 + fr, acc[mf][nf][r]);
        }
      }
}

extern "C" void kernel_launch(void* const* d_in, const int* in_sizes, int n_in,
                              void* d_out, int out_size, void* d_ws, size_t ws_size,
                              hipStream_t stream) {
  const float* x       = (const float*)d_in[0];
  const float* weights = (const float*)d_in[1];
  const int*   indices = (const int*)d_in[2];
  const float* Wg      = (const float*)d_in[3];
  const float* Wu      = (const float*)d_in[4];
  const float* Wd      = (const float*)d_in[5];
  float* y = (float*)d_out;

  const size_t WELEM = (size_t)NE * DINTER * DMODEL;  // 46.1M elems per weight tensor

  char* ws = (char*)d_ws;
  size_t o = 0;
  float* gate_w = (float*)(ws + o); o += (size_t)TT * NE * 4;       // 131072
  size_t ctrlOff = o;
  int* counts = (int*)(ws + o);
  int* offs   = (int*)(ws + o + 64);
  int* cursor = (int*)(ws + o + 192);
  o += 256;
  int*   slot_tok  = (int*)(ws + o);   o += (size_t)PMAX * 4;
  float* slot_gate = (float*)(ws + o); o += (size_t)PMAX * 4;
  u16* xb  = (u16*)(ws + o); o += (size_t)TT * DMODEL * 2;
  u16* act = (u16*)(ws + o); o += (size_t)(PMAX + 256) * DINTER * 2; // pad rows
  u16* wgb = (u16*)(ws + o); o += WELEM * 2;
  u16* wub = (u16*)(ws + o); o += WELEM * 2;
  u16* wdb = (u16*)(ws + o); o += WELEM * 2;   // total ~306 MB
  (void)ws_size; (void)in_sizes; (void)n_in;

  hipMemsetAsync(d_out, 0, (size_t)out_size * 4, stream);
  hipMemsetAsync(ws + ctrlOff, 0, 256, stream);

  k_gate<<<TT * NE / 256, 256, 0, stream>>>(weights, indices, gate_w, counts);
  k_scan<<<1, 64, 0, stream>>>(counts, offs);
  k_fill<<<TT * NE / 256, 256, 0, stream>>>(gate_w, offs, cursor, slot_tok, slot_gate);
  k_castall<<<2048, 256, 0, stream>>>(x, xb, Wg, wgb, Wu, wub, Wd, wdb);
  k_gemm1<<<1408, 512, 0, stream>>>(xb, wgb, wub, slot_tok, slot_gate, offs, counts, act);
  k_gemm2<<<4096, 256, 0, stream>>>(act, wdb, slot_tok, offs, counts, y);
}